// Round 11
// baseline (268.102 us; speedup 1.0000x reference)
//
#include <hip/hip_runtime.h>

using i32x4 = __attribute__((ext_vector_type(4))) int;

#define AS3(p) ((__attribute__((address_space(3))) void*)(p))
#define AS1(p) ((const __attribute__((address_space(1))) void*)(p))

constexpr int M = 8192;
constexpr int N = 4096;
constexpr int K = 4096;
constexpr int BK = 64;           // 64 B/row per K-tile
constexpr int NT = K / BK;       // 64 K-tiles
constexpr int NBUF = 3;          // A-only LDS ring (16 KB/slot -> 48 KB)

// ---------------- Pass 1a: pack x (int32 -> int8), layout preserved [M][K] ----------------
__global__ void pack_a_kernel(const int4* __restrict__ x, unsigned* __restrict__ a8, int nUnits) {
    int stride = gridDim.x * blockDim.x;
    for (int u = blockIdx.x * blockDim.x + threadIdx.x; u < nUnits; u += stride) {
        int4 v = x[u];
        a8[u] = (v.x & 255) | ((v.y & 255) << 8) | ((v.z & 255) << 16) | (v.w << 24);
    }
}

// ---------------- Pass 1b: pack + transpose W: [K][N] int32 -> [N][K] int8 ----------------
__global__ void pack_wT_kernel(const int* __restrict__ w, char* __restrict__ b8t) {
    __shared__ __align__(16) char T[64][80];
    const int n0 = blockIdx.x * 64;
    const int k0 = blockIdx.y * 64;
    const int tid = threadIdx.x;

    #pragma unroll
    for (int i = 0; i < 4; i++) {
        int u = tid + i * 256;
        int r = u >> 4;
        int c = u & 15;
        int4 v = *(const int4*)&w[(size_t)(k0 + r) * N + n0 + 4 * c];
        T[4 * c + 0][r] = (char)v.x;
        T[4 * c + 1][r] = (char)v.y;
        T[4 * c + 2][r] = (char)v.z;
        T[4 * c + 3][r] = (char)v.w;
    }
    __syncthreads();

    const int n = tid >> 2;
    const int q = tid & 3;
    int4 val = *(const int4*)&T[n][16 * q];
    *(int4*)&b8t[(size_t)(n0 + n) * K + k0 + 16 * q] = val;
}

// ---------------- Pass 2: i8 GEMM, 256x256 tile, A via LDS, B DIRECT global->reg ----------------
// 10-round model: LDS-reads + MFMA serialize per CU no matter the schedule. Cut LDS work:
// B fragments load straight from global (L2-resident panel) into regs with the SAME
// lane->(col,kchunk) mapping the LDS path used (row = bcol+wc*64+n*16+(lane&15), kchunk =
// (lane>>4)*16) -> layout identical to the absmax-0-verified path. B(t+1) issues at tile t
// (full-tile latency slack); compiler inserts the counted vmcnt for the register dep, and
// FIFO order makes that wait also drain the older stage(t+1). Manual waits: one vmcnt(6)
// per tile (stage->ds_read hazard; raw s_barrier does NOT drain counters) + lgkmcnt(0) at
// tile end (slot WAR). LDS traffic/tile: A reads 64 KB + writes 16 KB (was 96+32).
__global__ __launch_bounds__(512, 2) void gemm_i8_kernel(
    const char* __restrict__ a8, const char* __restrict__ b8t,
    const int* __restrict__ bias, const float* __restrict__ scales,
    float* __restrict__ out)
{
    __shared__ __align__(16) char As[NBUF][256 * BK];   // 16 KB each, 48 KB total

    const int tid  = threadIdx.x;
    const int lane = tid & 63;
    const int wid  = tid >> 6;
    const int wr   = wid >> 2;   // 0..1 -> 128-row band
    const int wc   = wid & 3;    // 0..3 -> 64-col band

    // XCD-aware remap: each XCD covers an 8x8 (tm,tn) square (FETCH 148->98 MB, R3)
    const int bid = blockIdx.x;
    const int xcd = bid & 7;
    const int l   = bid >> 3;
    const int tm  = (xcd >> 1) * 8 + (l >> 3);   // 0..31
    const int tn  = (xcd & 1) * 8 + (l & 7);     // 0..15
    const size_t brow = (size_t)tm * 256;
    const size_t bcol = (size_t)tn * 256;

    // A staging: 2 gll/thread/tile (rows srow, srow+128), srow = tid>>2, chunk tid&3
    // pre-swizzled by ((srow>>1)&3) (rule #21; PMC-verified 0 conflicts since R2).
    const int srow = tid >> 2;
    const int schS = ((tid & 3) ^ ((tid >> 3) & 3)) << 4;
    const char* aGs = a8 + (brow + srow) * (size_t)K + schS;
    const int ldsW = wid * 1024;   // wave-uniform dest; HW adds lane*16

    // B direct-load base: col = bcol + wc*64 + (lane&15), kchunk = (lane>>4)*16.
    const char* bBase = b8t + (bcol + wc * 64 + (lane & 15)) * (size_t)K + ((lane >> 4) << 4);

    i32x4 acc[8][4];
    #pragma unroll
    for (int m = 0; m < 8; m++)
        #pragma unroll
        for (int n = 0; n < 4; n++)
            #pragma unroll
            for (int r = 0; r < 4; r++)
                acc[m][n][r] = 0;

    auto stage = [&](int slot, int kt) {
        const char* a = aGs + (size_t)kt * BK;
        __builtin_amdgcn_global_load_lds(AS1(a),                 AS3(&As[slot][ldsW]),        16, 0, 0);
        __builtin_amdgcn_global_load_lds(AS1(a + (size_t)128*K), AS3(&As[slot][8192 + ldsW]), 16, 0, 0);
    };
    auto loadB = [&](i32x4 (&dst)[4], int kt) {
        #pragma unroll
        for (int n = 0; n < 4; ++n)
            dst[n] = *(const i32x4*)(bBase + (size_t)n * 16 * K + (size_t)kt * BK);
    };

    // A fragment reads: row = wr*128 + m*16 + frow; chunk = lane>>4 swizzled by ((frow>>1)&3).
    const int frow = lane & 15;
    const int c0sw = ((lane >> 4) ^ ((frow >> 1) & 3)) << 4;
    const int raOff = wr * 8192 + frow * 64 + c0sw;

    i32x4 bA[4], bB[4];   // two named B sets (rule #20)

    // Prologue: B(0) first, then stages -> counted drain vmcnt(2) covers B(0)+stage(0).
    loadB(bA, 0);
    stage(0, 0);
    stage(1, 1);
    asm volatile("s_waitcnt vmcnt(2)" ::: "memory");
    __builtin_amdgcn_s_barrier();

    int s0 = 0;
    auto body = [&](int t, i32x4 (&bC)[4], i32x4 (&bN)[4]) {
        int sp = s0 + 2; if (sp >= 3) sp -= 3;
        if (t + 2 < NT) stage(sp, t + 2);
        if (t + 1 < NT) loadB(bN, t + 1);
        // drain everything except the 6 newest ops (this tile's stage+loadB):
        // guarantees stage(t+1) landed and B(t) available regardless of issue order.
        asm volatile("s_waitcnt vmcnt(6)" ::: "memory");

        const char* Ab = &As[s0][0] + raOff;
        __builtin_amdgcn_s_setprio(1);
        #pragma unroll
        for (int m = 0; m < 8; ++m) {
            i32x4 af = *(const i32x4*)(Ab + m * 1024);   // compiler interleaves lgkmcnt (m97 pattern)
            #pragma unroll
            for (int n = 0; n < 4; ++n)
                acc[m][n] = __builtin_amdgcn_mfma_i32_16x16x64_i8(af, bC[n], acc[m][n], 0, 0, 0);
        }
        __builtin_amdgcn_s_setprio(0);

        asm volatile("s_waitcnt lgkmcnt(0)" ::: "memory");  // my slot-s0 reads done (WAR)
        __builtin_amdgcn_s_barrier();                       // slot s0 free for restage at t+1
        s0 = (s0 == 2) ? 0 : s0 + 1;
    };

    for (int t = 0; t < NT; t += 2) {   // NT even: static double-buffer swap
        body(t,     bA, bB);
        body(t + 1, bB, bA);
    }

    // epilogue: D col = lane&15 (N-dim), row = (lane>>4)*4 + reg (absmax 0 in r1-r10)
    #pragma unroll
    for (int n = 0; n < 4; ++n) {
        const int col = (int)bcol + wc * 64 + n * 16 + (lane & 15);
        const int bv  = bias[col];
        const float sv = scales[col];
        #pragma unroll
        for (int m = 0; m < 8; ++m) {
            const size_t row0 = brow + wr * 128 + m * 16 + ((lane >> 4) << 2);
            float* o = out + row0 * (size_t)N + col;
            #pragma unroll
            for (int r = 0; r < 4; ++r)
                o[(size_t)r * N] = (float)(acc[m][n][r] + bv) * sv;
        }
    }
}

extern "C" void kernel_launch(void* const* d_in, const int* in_sizes, int n_in,
                              void* d_out, int out_size, void* d_ws, size_t ws_size,
                              hipStream_t stream) {
    const int*   x      = (const int*)d_in[0];
    const int*   w      = (const int*)d_in[1];
    const int*   bias   = (const int*)d_in[2];
    const float* scales = (const float*)d_in[3];
    float* out = (float*)d_out;

    char* a8  = (char*)d_ws;                       // M*K = 32 MB
    char* b8t = a8 + (size_t)M * K;                // N*K = 16 MB

    pack_a_kernel<<<2048, 256, 0, stream>>>((const int4*)x, (unsigned*)a8, M * K / 4);

    dim3 gt(N / 64, K / 64);
    pack_wT_kernel<<<gt, 256, 0, stream>>>(w, b8t);

    gemm_i8_kernel<<<(M / 256) * (N / 256), 512, 0, stream>>>(a8, b8t, bias, scales, out);
}